// Round 13
// baseline (232.867 us; speedup 1.0000x reference)
//
#include <hip/hip_runtime.h>
#include <math.h>

#define N_POSE   1024
#define M_TRAIN  10000
#define NJOINT   21
#define KNEIGH   5
#define CLIPV    (1.0f - 1e-7f)
#define HPI_F    1.57079632679490f
#define BIGF     1e30f
#define TPB      256
#define NBROWS   64          // query rows per block (shared by its 4 waves)
#define MSUB     4           // m-subchunks per block (one per wave)
#define QT_FLOATS (N_POSE * NJOINT * 4)   // transposed normalized q in ws

// prepass: normalize all query quats AND transpose to [nb][j][r] so the hot
// loop reads them coalesced (lane r -> base(j) + r*16) and L1-resident.
__global__ __launch_bounds__(256)
void pose_norm_t_kernel(const float* __restrict__ pose, float* __restrict__ qT) {
    int i = blockIdx.x * blockDim.x + threadIdx.x;   // i = n*21 + j
    if (i >= N_POSE * NJOINT) return;
    int n = i / NJOINT, j = i % NJOINT;
    float4 v = ((const float4*)pose)[i];
    float inv = rsqrtf(v.x * v.x + v.y * v.y + v.z * v.z + v.w * v.w);
    v.x *= inv; v.y *= inv; v.z *= inv; v.w *= inv;
    ((float4*)qT)[(((n >> 6) * NJOINT + j) << 6) + (n & 63)] = v;
}

// thread = query row, but q is NOT register-resident (the 12-round register
// war is over): per (m,j) it is re-read from the transposed L1-resident qT
// (21.5 KB per block, coalesced saddr-form loads, LICM defeated via opaque
// asm on the scalar base). Train (wave-uniform) flows through s_load/SGPRs.
// Per-thread live state ~25 floats -> no spill at any allocator budget.
__global__ __launch_bounds__(TPB)
void pose_dist_kernel(const float* __restrict__ qT,
                      const float* __restrict__ train,
                      float* __restrict__ topk,
                      int chunks, int mchunk) {
    const int nb   = blockIdx.x / chunks;     // row-group (64 rows)
    const int cb   = blockIdx.x % chunks;
    const int wave = threadIdx.x >> 6;        // m-quarter owner
    const int lane = threadIdx.x & 63;
    const int n    = nb * NBROWS + lane;

    const int mq   = mchunk / MSUB;
    const int mbeg = cb * mchunk + wave * mq;

    uintptr_t qbi = (uintptr_t)(qT + (size_t)nb * (NJOINT * NBROWS * 4));
    const int vlane = lane * 16;              // the ONE per-lane byte offset
    const char* tb = (const char*)train + (size_t)mbeg * 336;

    float t0 = BIGF, t1 = BIGF, t2 = BIGF, t3 = BIGF, t4 = BIGF;

#pragma unroll 1
    for (int mi = 0; mi < mq; ++mi) {
        asm volatile("" : "+s"(qbi));         // defeat LICM: q loads stay in-loop
        const char* qc = (const char*)qbi;
        const float4* __restrict__ tm = (const float4*)(tb + (size_t)mi * 336);
        float a0 = 0.f, a1 = 0.f;
#pragma unroll
        for (int j = 0; j < NJOINT; ++j) {
            float4 u = tm[j];                 // wave-uniform -> s_load (SGPRs)
            float4 p = *(const float4*)(qc + j * (NBROWS * 16) + vlane);
            float d = u.x * p.x + u.y * p.y + u.z * p.z + u.w * p.w;
            float a = fminf(fabsf(d), CLIPV);
            float pl = fmaf(a, -0.0187293f, 0.0742610f);
            pl = fmaf(a, pl, -0.2121144f);
            pl = fmaf(a, pl, 1.5707288f);
            float r  = __builtin_amdgcn_sqrtf(1.0f - a) * pl;
            float cs = __builtin_copysignf(HPI_F - r, d);
            if (j & 1) a1 += cs; else a0 += cs;
        }
        float v = (NJOINT * HPI_F - (a0 + a1)) * 0.5f;
        t4 = fminf(t4, fmaxf(t3, v));
        t3 = fminf(t3, fmaxf(t2, v));
        t2 = fminf(t2, fmaxf(t1, v));
        t1 = fminf(t1, fmaxf(t0, v));
        t0 = fminf(t0, v);
    }

    // effective chunk id = cb*MSUB + wave; [cbEff][n][k] coalesced-ish
    float* w = topk + ((size_t)(cb * MSUB + wave) * N_POSE + n) * KNEIGH;
    w[0] = t0; w[1] = t1; w[2] = t2; w[3] = t3; w[4] = t4;
}

// one wave per query row: merge chunksEff*5 candidates -> mean of top-5
__global__ __launch_bounds__(64)
void pose_reduce_kernel(const float* __restrict__ topk, float* __restrict__ out,
                        int chunksEff) {
    const int n = blockIdx.x;
    const int lane = threadIdx.x;
    const int total = chunksEff * KNEIGH;

    float t0 = BIGF, t1 = BIGF, t2 = BIGF, t3 = BIGF, t4 = BIGF;
    for (int i = lane; i < total; i += 64) {
        int cb = i / KNEIGH, k = i % KNEIGH;
        float v = topk[((size_t)cb * N_POSE + n) * KNEIGH + k];
        t4 = fminf(t4, fmaxf(t3, v));
        t3 = fminf(t3, fmaxf(t2, v));
        t2 = fminf(t2, fmaxf(t1, v));
        t1 = fminf(t1, fmaxf(t0, v));
        t0 = fminf(t0, v);
    }

    float sum = 0.f;
#pragma unroll
    for (int r = 0; r < KNEIGH; ++r) {
        float v = t0; int who = lane;
        for (int off = 32; off; off >>= 1) {
            float ov = __shfl_xor(v, off);
            int   ow = __shfl_xor(who, off);
            if (ov < v || (ov == v && ow < who)) { v = ov; who = ow; }
        }
        sum += v;
        if (lane == who) { t0 = t1; t1 = t2; t2 = t3; t3 = t4; t4 = BIGF; }
    }
    if (lane == 0) out[n] = sum * (1.0f / KNEIGH);
}

extern "C" void kernel_launch(void* const* d_in, const int* in_sizes, int n_in,
                              void* d_out, int out_size, void* d_ws, size_t ws_size,
                              hipStream_t stream) {
    const float* pose  = (const float*)d_in[0];
    const float* train = (const float*)d_in[1];
    float* out  = (float*)d_out;
    float* qT   = (float*)d_ws;                 // QT_FLOATS floats
    float* topk = (float*)d_ws + QT_FLOATS;

    // tiers divide 10000 with mchunk % 4 == 0; topk area = chunks*4*1024*5*4 B
    size_t base = (size_t)QT_FLOATS * sizeof(float);
    int chunks = 125;
    if (base + (size_t)chunks * MSUB * N_POSE * KNEIGH * sizeof(float) > ws_size) chunks = 50;
    if (base + (size_t)chunks * MSUB * N_POSE * KNEIGH * sizeof(float) > ws_size) chunks = 25;
    if (base + (size_t)chunks * MSUB * N_POSE * KNEIGH * sizeof(float) > ws_size) chunks = 10;
    const int mchunk = M_TRAIN / chunks;

    pose_norm_t_kernel<<<dim3((N_POSE * NJOINT + 255) / 256), dim3(256), 0, stream>>>(pose, qT);

    dim3 grid1((N_POSE / NBROWS) * chunks);   // 16 row-groups x 125 = 2000 blocks
    pose_dist_kernel<<<grid1, dim3(TPB), 0, stream>>>(qT, train, topk, chunks, mchunk);

    pose_reduce_kernel<<<dim3(N_POSE), dim3(64), 0, stream>>>(topk, out, chunks * MSUB);
}

// Round 14
// 113.132 us; speedup vs baseline: 2.0584x; 2.0584x over previous
//
#include <hip/hip_runtime.h>
#include <math.h>

#define N_POSE   1024
#define M_TRAIN  10000
#define NJOINT   21
#define KNEIGH   5
#define CLIPV    (1.0f - 1e-7f)
#define HPI_F    1.57079632679490f
#define BIGF     1e30f
#define TPB      256
#define MB       8                        // m-values per register block
#define QT_FLOATS (N_POSE * NJOINT * 4)   // transposed normalized q in ws

// prepass: normalize query quats AND transpose to [j][n] so the hot loop's
// q-load is coalesced (lane n -> qT + (j*1024+n)*16B, 1024B/instr).
__global__ __launch_bounds__(256)
void pose_norm_t_kernel(const float* __restrict__ pose, float* __restrict__ qT) {
    int i = blockIdx.x * blockDim.x + threadIdx.x;   // i = n*21 + j
    if (i >= N_POSE * NJOINT) return;
    int n = i / NJOINT, j = i % NJOINT;
    float4 v = ((const float4*)pose)[i];
    float inv = rsqrtf(v.x * v.x + v.y * v.y + v.z * v.z + v.w * v.w);
    v.x *= inv; v.y *= inv; v.z *= inv; v.w *= inv;
    ((float4*)qT)[(size_t)j * N_POSE + n] = v;
}

// j-outer / m-inner register blocking.
//  - q[j] loaded ONCE per (j, 8-m block) from transposed qT: coalesced 16B/lane
//    (kills the 336B-stride 64-line gathers that inflated every prior round).
//  - train via s_load (addresses derived ONLY from blockIdx -> provably
//    wave-uniform -> SGPRs; 8 loads pipeline per j, K$-resident chunk).
//  - per-thread live state ~29 floats: acc[8]+q(4+4)+top5+temps -> fits the
//    allocator's budget by construction; nothing to remat or spill.
__global__ __launch_bounds__(TPB)
void pose_dist_kernel(const float* __restrict__ qT,
                      const float* __restrict__ train,
                      float* __restrict__ topk,
                      int chunks, int mchunk) {
    const int nb = blockIdx.x / chunks;   // row-group (0..3)
    const int cb = blockIdx.x % chunks;   // m-chunk
    const int n  = nb * TPB + threadIdx.x;

    const char* tb = (const char*)train + (size_t)cb * mchunk * 336;
    const float4* __restrict__ qbase = (const float4*)qT + n;   // + j*1024 per j

    float t0 = BIGF, t1 = BIGF, t2 = BIGF, t3 = BIGF, t4 = BIGF;

#pragma unroll 1
    for (int mb = 0; mb < mchunk; mb += MB) {
        const char* tmb = tb + (size_t)mb * 336;
        float acc0 = 0.f, acc1 = 0.f, acc2 = 0.f, acc3 = 0.f;
        float acc4 = 0.f, acc5 = 0.f, acc6 = 0.f, acc7 = 0.f;

        float4 qc = qbase[0];                       // j = 0
#pragma unroll 1
        for (int j = 0; j < NJOINT; ++j) {
            float4 qnx = qbase[(j + 1 < NJOINT ? j + 1 : 0) * N_POSE]; // prefetch
#pragma unroll
            for (int mm = 0; mm < MB; ++mm) {
                float4 u = *(const float4*)(tmb + mm * 336 + j * 16); // s_load
                float d = u.x * qc.x + u.y * qc.y + u.z * qc.z + u.w * qc.w;
                float a = fminf(fabsf(d), CLIPV);
                float pl = fmaf(a, -0.0187293f, 0.0742610f);
                pl = fmaf(a, pl, -0.2121144f);
                pl = fmaf(a, pl, 1.5707288f);
                float r  = __builtin_amdgcn_sqrtf(1.0f - a) * pl;
                float cs = __builtin_copysignf(HPI_F - r, d);
                if      (mm == 0) acc0 += cs; else if (mm == 1) acc1 += cs;
                else if (mm == 2) acc2 += cs; else if (mm == 3) acc3 += cs;
                else if (mm == 4) acc4 += cs; else if (mm == 5) acc5 += cs;
                else if (mm == 6) acc6 += cs; else               acc7 += cs;
            }
            qc = qnx;
        }

        float accs[MB] = {acc0, acc1, acc2, acc3, acc4, acc5, acc6, acc7};
#pragma unroll
        for (int mm = 0; mm < MB; ++mm) {
            float v = (NJOINT * HPI_F - accs[mm]) * 0.5f;
            t4 = fminf(t4, fmaxf(t3, v));
            t3 = fminf(t3, fmaxf(t2, v));
            t2 = fminf(t2, fmaxf(t1, v));
            t1 = fminf(t1, fmaxf(t0, v));
            t0 = fminf(t0, v);
        }
    }

    // [n][cb][k]: reduce reads each row contiguously (coalesced)
    float* w = topk + ((size_t)n * chunks + cb) * KNEIGH;
    w[0] = t0; w[1] = t1; w[2] = t2; w[3] = t3; w[4] = t4;
}

// one wave per query row: merge chunks*5 candidates -> mean of top-5
__global__ __launch_bounds__(64)
void pose_reduce_kernel(const float* __restrict__ topk, float* __restrict__ out,
                        int chunks) {
    const int n = blockIdx.x;
    const int lane = threadIdx.x;
    const int total = chunks * KNEIGH;
    const float* __restrict__ w = topk + (size_t)n * total;

    float t0 = BIGF, t1 = BIGF, t2 = BIGF, t3 = BIGF, t4 = BIGF;
    for (int i = lane; i < total; i += 64) {
        float v = w[i];
        t4 = fminf(t4, fmaxf(t3, v));
        t3 = fminf(t3, fmaxf(t2, v));
        t2 = fminf(t2, fmaxf(t1, v));
        t1 = fminf(t1, fmaxf(t0, v));
        t0 = fminf(t0, v);
    }

    float sum = 0.f;
#pragma unroll
    for (int r = 0; r < KNEIGH; ++r) {
        float v = t0; int who = lane;
        for (int off = 32; off; off >>= 1) {
            float ov = __shfl_xor(v, off);
            int   ow = __shfl_xor(who, off);
            if (ov < v || (ov == v && ow < who)) { v = ov; who = ow; }
        }
        sum += v;
        if (lane == who) { t0 = t1; t1 = t2; t2 = t3; t3 = t4; t4 = BIGF; }
    }
    if (lane == 0) out[n] = sum * (1.0f / KNEIGH);
}

extern "C" void kernel_launch(void* const* d_in, const int* in_sizes, int n_in,
                              void* d_out, int out_size, void* d_ws, size_t ws_size,
                              hipStream_t stream) {
    const float* pose  = (const float*)d_in[0];
    const float* train = (const float*)d_in[1];
    float* out  = (float*)d_out;
    float* qT   = (float*)d_ws;                 // QT_FLOATS floats
    float* topk = (float*)d_ws + QT_FLOATS;

    // tiers divide 10000 and keep mchunk % 8 == 0
    size_t base = (size_t)QT_FLOATS * sizeof(float);
    int chunks = 250;
    if (base + (size_t)N_POSE * chunks * KNEIGH * sizeof(float) > ws_size) chunks = 125;
    if (base + (size_t)N_POSE * chunks * KNEIGH * sizeof(float) > ws_size) chunks = 50;
    if (base + (size_t)N_POSE * chunks * KNEIGH * sizeof(float) > ws_size) chunks = 10;
    const int mchunk = M_TRAIN / chunks;

    pose_norm_t_kernel<<<dim3((N_POSE * NJOINT + 255) / 256), dim3(256), 0, stream>>>(pose, qT);

    dim3 grid1((N_POSE / TPB) * chunks);   // 4 row-groups x 250 chunks = 1000 blocks
    pose_dist_kernel<<<grid1, dim3(TPB), 0, stream>>>(qT, train, topk, chunks, mchunk);

    pose_reduce_kernel<<<dim3(N_POSE), dim3(64), 0, stream>>>(topk, out, chunks);
}